// Round 2
// baseline (8783.733 us; speedup 1.0000x reference)
//
#include <hip/hip_runtime.h>
#include <hip/hip_bf16.h>

// ConstGateRNN: B=64, T=512, D=128, H=512, s=0.7 (const).
// out = concat(y[64*512], hseq[64*512*512], gate(=0.7), leak(=0.3), rdiag) f32.
//
// Plan:
//  1) fill_consts: gate/leak constant regions (134 MB stores).
//  2) zero_cnt: zero the group-barrier counters in ws (ws is 0xAA-poisoned).
//  3) xw_gemm: xw = x@Wx^T + b, written into the RDIAG region (read at step t,
//     overwritten by rdiag at step t by the same thread -> no extra ws).
//  4) scan_rnn (cooperative, 512 blocks x 256): 16 groups x 4 batches;
//     32 blocks/group each owning 16 h-rows with Wh slice persistent in LDS.
//     Per step: stage h_prev (agent-scope atomic loads from ws double-buffer),
//     f32 dot via 4-wave k-split + shfl reduce, tanh/blend epilogue, write
//     hseq+rdiag+hbuf, one group barrier (release add / acquire poll).
//     LDS/block = 42.3 KB -> 2 blocks/CU co-resident (512 blocks OK).
//  5) y_proj: y = hseq @ out_w^T + out_b.

static constexpr float SC = 0.7f;

static constexpr long long OFF_Y     = 0;
static constexpr long long OFF_HSEQ  = 32768;
static constexpr long long OFF_GATE  = 32768LL + 16777216LL;
static constexpr long long OFF_LEAK  = OFF_GATE + 16777216LL;
static constexpr long long OFF_RDIAG = OFF_LEAK + 16777216LL;

__global__ __launch_bounds__(256) void fill_consts(float* __restrict__ gate,
                                                   float* __restrict__ leak) {
    const float s = SC, l = 1.0f - SC;
    const float4 s4 = make_float4(s, s, s, s);
    const float4 l4 = make_float4(l, l, l, l);
    float4* g4 = (float4*)gate;
    float4* k4 = (float4*)leak;
    const int n4 = 16777216 / 4;
    for (int i = blockIdx.x * blockDim.x + threadIdx.x; i < n4;
         i += gridDim.x * blockDim.x) {
        g4[i] = s4;
        k4[i] = l4;
    }
}

__global__ void zero_cnt(unsigned* cnt) { cnt[threadIdx.x] = 0u; }

// xw = x @ Wx^T + Wx_b   ([32768,128] x [512,128]^T -> [32768,512])
__global__ __launch_bounds__(256) void xw_gemm(const float* __restrict__ x,
                                               const float* __restrict__ Wx,
                                               const float* __restrict__ Wxb,
                                               float* __restrict__ out) {
    __shared__ float xs[32 * 132];
    const int m0 = blockIdx.x * 32;
    const int n0 = blockIdx.y * 64;
    const int tid = threadIdx.x;
    const float4* x4 = (const float4*)x + (long long)m0 * 32;  // 128 f32 = 32 f4/row
    float4* xs4 = (float4*)xs;
    for (int q = tid; q < 32 * 32; q += 256) {
        int r = q >> 5, c = q & 31;
        xs4[r * 33 + c] = x4[r * 32 + c];
    }
    __syncthreads();
    const int mg = tid >> 4;  // 0..15 -> rows mg*2, mg*2+1
    const int ng = tid & 15;  // 0..15 -> cols n0+ng*4 ..+3
    const float4* w4 = (const float4*)Wx;
    const int nb = n0 + ng * 4;
    float acc[2][4] = {};
#pragma unroll 8
    for (int dq = 0; dq < 32; ++dq) {
        float4 xv0 = xs4[(mg * 2) * 33 + dq];
        float4 xv1 = xs4[(mg * 2 + 1) * 33 + dq];
#pragma unroll
        for (int j = 0; j < 4; ++j) {
            float4 wv = w4[(long long)(nb + j) * 32 + dq];
            acc[0][j] += xv0.x * wv.x + xv0.y * wv.y + xv0.z * wv.z + xv0.w * wv.w;
            acc[1][j] += xv1.x * wv.x + xv1.y * wv.y + xv1.z * wv.z + xv1.w * wv.w;
        }
    }
#pragma unroll
    for (int i = 0; i < 2; ++i)
#pragma unroll
        for (int j = 0; j < 4; ++j)
            out[(long long)(m0 + mg * 2 + i) * 512 + nb + j] = acc[i][j] + Wxb[nb + j];
}

// Persistent cooperative scan. 512 blocks x 256 threads.
// group g = blockIdx&15 (4 batches), j = blockIdx>>4 (16 h-rows).
__global__ __launch_bounds__(256, 2) void scan_rnn(const float* __restrict__ Wh,
                                                   float* __restrict__ xwrd,  // xw in / rdiag out
                                                   float* __restrict__ hseq,
                                                   float* hbuf,
                                                   unsigned* cnt) {
    __shared__ float wl[16 * 516];
    __shared__ float hp[4 * 516];
    __shared__ float part[256];
    const int tid = threadIdx.x;
    const int g = blockIdx.x & 15;
    const int j = blockIdx.x >> 4;
    const int bbase = g * 4, rbase = j * 16;

    {   // stage Wh rows [rbase, rbase+16) once (persistent across all steps)
        const float4* wh4 = (const float4*)Wh;
        float4* wl4s = (float4*)wl;
        for (int q = tid; q < 16 * 128; q += 256) {
            int r = q >> 7, c = q & 127;
            wl4s[r * 129 + c] = wh4[(long long)(rbase + r) * 128 + c];
        }
    }
    __syncthreads();

    const int wave = tid >> 6, lane = tid & 63;
    const int rg = lane >> 3, ksl = lane & 7;
    const int kq0 = wave * 32 + ksl * 4;  // float4 index base of this lane's k range
    const float LEAK = 1.0f - SC;
    const float4* wl4 = (const float4*)wl;
    const float4* hp4 = (const float4*)hp;

    for (int t = 0; t < 512; ++t) {
        // ---- stage h_prev (full 512 per batch) ----
        if (t == 0) {
            for (int i = tid; i < 4 * 516; i += 256) hp[i] = 0.0f;
        } else {
            const int b = tid >> 6, ks = tid & 63;
            const float* src = hbuf + ((t & 1) ^ 1) * 32768 + (long long)(bbase + b) * 512;
#pragma unroll
            for (int jj = 0; jj < 8; ++jj) {
                int k = ks + jj * 64;
                hp[b * 516 + k] =
                    __hip_atomic_load(src + k, __ATOMIC_RELAXED, __HIP_MEMORY_SCOPE_AGENT);
            }
        }
        __syncthreads();

        // ---- compute: 4 waves split K, lane tile = 4 batches x 2 rows x 16 k ----
        float acc[2][4] = {};
#pragma unroll
        for (int kk = 0; kk < 4; ++kk) {
            const int k4 = kq0 + kk;
            float4 w0 = wl4[(rg * 2) * 129 + k4];
            float4 w1 = wl4[(rg * 2 + 1) * 129 + k4];
#pragma unroll
            for (int b = 0; b < 4; ++b) {
                float4 hv = hp4[b * 129 + k4];
                acc[0][b] += w0.x * hv.x + w0.y * hv.y + w0.z * hv.z + w0.w * hv.w;
                acc[1][b] += w1.x * hv.x + w1.y * hv.y + w1.z * hv.z + w1.w * hv.w;
            }
        }
#pragma unroll
        for (int rr = 0; rr < 2; ++rr)
#pragma unroll
            for (int b = 0; b < 4; ++b) {
                float v = acc[rr][b];
                v += __shfl_xor(v, 1);
                v += __shfl_xor(v, 2);
                v += __shfl_xor(v, 4);
                acc[rr][b] = v;
            }
        if (ksl == 0) {
#pragma unroll
            for (int rr = 0; rr < 2; ++rr)
#pragma unroll
                for (int b = 0; b < 4; ++b)
                    part[wave * 64 + (rg * 2 + rr) * 4 + b] = acc[rr][b];
        }
        __syncthreads();

        // ---- epilogue: 64 outputs ----
        if (tid < 64) {
            const int o = tid, r = o >> 2, b = o & 3;
            const int ar = rbase + r, gb = bbase + b;
            const long long idx = (long long)gb * 262144 + (long long)t * 512 + ar;
            float pre = part[o] + part[64 + o] + part[128 + o] + part[192 + o] + xwrd[idx];
            float th = tanhf(pre);
            float hpv = hp[b * 516 + ar];
            float h = LEAK * hpv + SC * th;
            hseq[idx] = h;
            float wd = wl[r * 516 + ar];          // Wh[ar][ar]
            xwrd[idx] = SC * (1.0f - th * th) * wd;  // rdiag overwrites xw cell
            __hip_atomic_store(hbuf + (t & 1) * 32768 + gb * 512 + ar, h,
                               __ATOMIC_RELAXED, __HIP_MEMORY_SCOPE_AGENT);
        }
        __syncthreads();

        // ---- group barrier (32 blocks) ----
        if (tid == 0) {
            __hip_atomic_fetch_add(cnt + g * 64, 1u, __ATOMIC_ACQ_REL,
                                   __HIP_MEMORY_SCOPE_AGENT);
            const unsigned tgt = (unsigned)(t + 1) * 32u;
            while (__hip_atomic_load(cnt + g * 64, __ATOMIC_ACQUIRE,
                                     __HIP_MEMORY_SCOPE_AGENT) < tgt)
                __builtin_amdgcn_s_sleep(1);
        }
        __syncthreads();
    }
}

// y[p] = dot(hseq[p,:], out_w) + out_b;  one wave per (b,t)
__global__ __launch_bounds__(256) void y_proj(const float* __restrict__ hseq,
                                              const float* __restrict__ ow,
                                              const float* __restrict__ ob,
                                              float* __restrict__ y) {
    const int wave = threadIdx.x >> 6, lane = threadIdx.x & 63;
    const int p = blockIdx.x * 4 + wave;
    const float4* h4 = (const float4*)(hseq + (long long)p * 512);
    const float4* o4 = (const float4*)ow;
    float4 a0 = h4[lane * 2], a1 = h4[lane * 2 + 1];
    float4 b0 = o4[lane * 2], b1 = o4[lane * 2 + 1];
    float s = a0.x * b0.x + a0.y * b0.y + a0.z * b0.z + a0.w * b0.w +
              a1.x * b1.x + a1.y * b1.y + a1.z * b1.z + a1.w * b1.w;
#pragma unroll
    for (int off = 32; off > 0; off >>= 1) s += __shfl_down(s, off);
    if (lane == 0) y[p] = s + ob[0];
}

extern "C" void kernel_launch(void* const* d_in, const int* in_sizes, int n_in,
                              void* d_out, int out_size, void* d_ws, size_t ws_size,
                              hipStream_t stream) {
    const float* x   = (const float*)d_in[0];
    const float* Wxw = (const float*)d_in[1];
    const float* Wxb = (const float*)d_in[2];
    const float* Whw = (const float*)d_in[3];
    const float* ow  = (const float*)d_in[4];
    const float* ob  = (const float*)d_in[5];
    float* out   = (float*)d_out;
    float* y     = out + OFF_Y;
    float* hseq  = out + OFF_HSEQ;
    float* gate  = out + OFF_GATE;
    float* leak  = out + OFF_LEAK;
    float* rdiag = out + OFF_RDIAG;
    float* hbuf  = (float*)d_ws;                                    // 2*64*512 f32
    unsigned* cnt = (unsigned*)((char*)d_ws + 2 * 64 * 512 * 4);    // 1024 u32

    fill_consts<<<2048, 256, 0, stream>>>(gate, leak);
    zero_cnt<<<1, 1024, 0, stream>>>(cnt);
    xw_gemm<<<dim3(1024, 8), 256, 0, stream>>>(x, Wxw, Wxb, rdiag);

    {
        const float* WhA = Whw;
        float* xwrdA = rdiag;
        float* hseqA = hseq;
        float* hbufA = hbuf;
        unsigned* cntA = cnt;
        void* args[] = {(void*)&WhA, (void*)&xwrdA, (void*)&hseqA, (void*)&hbufA,
                        (void*)&cntA};
        hipLaunchCooperativeKernel((void*)scan_rnn, dim3(512), dim3(256), args, 0,
                                   stream);
    }

    y_proj<<<8192, 256, 0, stream>>>(hseq, ow, ob, y);
}

// Round 3
// 2344.829 us; speedup vs baseline: 3.7460x; 3.7460x over previous
//
#include <hip/hip_runtime.h>
#include <hip/hip_bf16.h>

// ConstGateRNN: B=64, T=512, D=128, H=512, s=0.7 (const).
// out = concat(y[64*512], hseq[64*512*512], gate(=0.7), leak(=0.3), rdiag) f32.
//
// R3 design: barrier-free tag-embedded dataflow scan.
//  - 32 groups x 16 blocks (512 blocks, cooperative). Group g owns batches
//    [2g,2g+2); block j owns h-rows [32j,32j+32) with its Wh slice in LDS.
//  - Publish: h as (tag<<32 | f32bits) u64 atomic (agent scope) into parity
//    buffer hbuf[t&1]. Consumers poll ONLY their 4 slots (one producer) for
//    tag==t-1; value rides with the tag -> no barrier, no fences, no flags.
//    Parity double-buffer + publish-after-consume => no overwrite races.
//    ws 0xAA poison != any tag (and tag compare is exact) => replay-safe.
//  - xw prefetch at iter top (independent of recurrence) hides HBM latency.
//  - k4 = wave*32 + ksl + 8*kk spreads b128 LDS reads uniformly over bank
//    quads (fixes the 1e8 conflict cycles of the contiguous-f4 split).

static constexpr float SC = 0.7f;

static constexpr long long OFF_Y     = 0;
static constexpr long long OFF_HSEQ  = 32768;
static constexpr long long OFF_GATE  = 32768LL + 16777216LL;
static constexpr long long OFF_LEAK  = OFF_GATE + 16777216LL;
static constexpr long long OFF_RDIAG = OFF_LEAK + 16777216LL;

__global__ __launch_bounds__(256) void fill_consts(float* __restrict__ gate,
                                                   float* __restrict__ leak) {
    const float s = SC, l = 1.0f - SC;
    const float4 s4 = make_float4(s, s, s, s);
    const float4 l4 = make_float4(l, l, l, l);
    float4* g4 = (float4*)gate;
    float4* k4 = (float4*)leak;
    const int n4 = 16777216 / 4;
    for (int i = blockIdx.x * blockDim.x + threadIdx.x; i < n4;
         i += gridDim.x * blockDim.x) {
        g4[i] = s4;
        k4[i] = l4;
    }
}

// xw = x @ Wx^T + Wx_b   ([32768,128] x [512,128]^T -> [32768,512])
__global__ __launch_bounds__(256) void xw_gemm(const float* __restrict__ x,
                                               const float* __restrict__ Wx,
                                               const float* __restrict__ Wxb,
                                               float* __restrict__ out) {
    __shared__ float xs[32 * 132];
    const int m0 = blockIdx.x * 32;
    const int n0 = blockIdx.y * 64;
    const int tid = threadIdx.x;
    const float4* x4 = (const float4*)x + (long long)m0 * 32;
    float4* xs4 = (float4*)xs;
    for (int q = tid; q < 32 * 32; q += 256) {
        int r = q >> 5, c = q & 31;
        xs4[r * 33 + c] = x4[r * 32 + c];
    }
    __syncthreads();
    const int mg = tid >> 4;
    const int ng = tid & 15;
    const float4* w4 = (const float4*)Wx;
    const int nb = n0 + ng * 4;
    float acc[2][4] = {};
#pragma unroll 8
    for (int dq = 0; dq < 32; ++dq) {
        float4 xv0 = xs4[(mg * 2) * 33 + dq];
        float4 xv1 = xs4[(mg * 2 + 1) * 33 + dq];
#pragma unroll
        for (int j = 0; j < 4; ++j) {
            float4 wv = w4[(long long)(nb + j) * 32 + dq];
            acc[0][j] += xv0.x * wv.x + xv0.y * wv.y + xv0.z * wv.z + xv0.w * wv.w;
            acc[1][j] += xv1.x * wv.x + xv1.y * wv.y + xv1.z * wv.z + xv1.w * wv.w;
        }
    }
#pragma unroll
    for (int i = 0; i < 2; ++i)
#pragma unroll
        for (int j = 0; j < 4; ++j)
            out[(long long)(m0 + mg * 2 + i) * 512 + nb + j] = acc[i][j] + Wxb[nb + j];
}

// Barrier-free dataflow scan. 512 blocks x 256 threads (cooperative).
// g = bid>>4 (batches [2g,2g+2)), j = bid&15 (rows [32j,32j+32)).
__global__ __launch_bounds__(256, 2) void scan_rnn(
    const float* __restrict__ Wh, float* __restrict__ xwrd,
    float* __restrict__ hseq, unsigned long long* __restrict__ hbuf) {
    __shared__ float wl[32 * 516];
    __shared__ float hp[2 * 516];
    __shared__ float part[256];
    const int tid = threadIdx.x;
    const int g = blockIdx.x >> 4;
    const int j = blockIdx.x & 15;
    const int bbase = g * 2, rbase = j * 32;

    {   // stage this block's 32 Wh rows (persistent all 512 steps)
        const float4* wh4 = (const float4*)Wh;
        float4* w4s = (float4*)wl;
        for (int q = tid; q < 32 * 128; q += 256) {
            int r = q >> 7, c = q & 127;
            w4s[r * 129 + c] = wh4[(long long)(rbase + r) * 128 + c];
        }
    }

    const int wave = tid >> 6, lane = tid & 63;
    const int rg = lane >> 3, ksl = lane & 7;
    // epilogue mapping (tid<64): output (row er, batch eb)
    const int er = (tid & 63) >> 1, eb = tid & 1;
    const int ar = rbase + er, gb = bbase + eb;
    // staging mapping: 4 consecutive u64 slots of one producer
    const int sb = tid >> 7;                 // batch within group
    const int sk = (tid & 127) * 4;          // k-base
    unsigned long long* const myslot = hbuf + (unsigned)(bbase + sb) * 512u + sk;

    __syncthreads();

    const float4* wl4 = (const float4*)wl;
    const float4* hp4 = (const float4*)hp;

    for (int t = 0; t < 512; ++t) {
        const long long eidx =
            (long long)gb * 262144 + (long long)t * 512 + ar;
        float xwf = 0.0f;
        if (tid < 64) xwf = xwrd[eidx];  // prefetch: independent of recurrence

        if (t == 0) {
            for (int i = tid; i < 2 * 516; i += 256) hp[i] = 0.0f;
        } else {
            const unsigned long long* src = myslot + (((t & 1) ^ 1) ? 32768u : 0u);
            const unsigned tg = (unsigned)(t - 1);
            unsigned long long v0, v1, v2, v3;
            for (;;) {
                v0 = __hip_atomic_load(src + 0, __ATOMIC_RELAXED, __HIP_MEMORY_SCOPE_AGENT);
                v1 = __hip_atomic_load(src + 1, __ATOMIC_RELAXED, __HIP_MEMORY_SCOPE_AGENT);
                v2 = __hip_atomic_load(src + 2, __ATOMIC_RELAXED, __HIP_MEMORY_SCOPE_AGENT);
                v3 = __hip_atomic_load(src + 3, __ATOMIC_RELAXED, __HIP_MEMORY_SCOPE_AGENT);
                if ((unsigned)(v0 >> 32) == tg && (unsigned)(v1 >> 32) == tg &&
                    (unsigned)(v2 >> 32) == tg && (unsigned)(v3 >> 32) == tg)
                    break;
                __builtin_amdgcn_s_sleep(1);
            }
            hp[sb * 516 + sk + 0] = __uint_as_float((unsigned)v0);
            hp[sb * 516 + sk + 1] = __uint_as_float((unsigned)v1);
            hp[sb * 516 + sk + 2] = __uint_as_float((unsigned)v2);
            hp[sb * 516 + sk + 3] = __uint_as_float((unsigned)v3);
        }
        __syncthreads();

        // 4 waves split K (128 each); lane: 4 rows x 2 batches x 16 k.
        float acc[4][2] = {};
#pragma unroll
        for (int kk = 0; kk < 4; ++kk) {
            const int k4 = wave * 32 + ksl + kk * 8;  // bank-quad-uniform
            float4 h0 = hp4[k4];
            float4 h1 = hp4[129 + k4];
#pragma unroll
            for (int rr = 0; rr < 4; ++rr) {
                float4 w = wl4[(rg * 4 + rr) * 129 + k4];
                acc[rr][0] += w.x * h0.x + w.y * h0.y + w.z * h0.z + w.w * h0.w;
                acc[rr][1] += w.x * h1.x + w.y * h1.y + w.z * h1.z + w.w * h1.w;
            }
        }
#pragma unroll
        for (int rr = 0; rr < 4; ++rr)
#pragma unroll
            for (int b = 0; b < 2; ++b) {
                float v = acc[rr][b];
                v += __shfl_xor(v, 1);
                v += __shfl_xor(v, 2);
                v += __shfl_xor(v, 4);
                acc[rr][b] = v;
            }
        if (ksl == 0) {
#pragma unroll
            for (int rr = 0; rr < 4; ++rr)
#pragma unroll
                for (int b = 0; b < 2; ++b)
                    part[wave * 64 + (rg * 4 + rr) * 2 + b] = acc[rr][b];
        }
        __syncthreads();

        if (tid < 64) {
            float pre = part[tid] + part[64 + tid] + part[128 + tid] +
                        part[192 + tid] + xwf;
            float th = tanhf(pre);
            float hpv = hp[eb * 516 + ar];
            float h = (1.0f - SC) * hpv + SC * th;
            // publish FIRST (value+tag in one atom -> consumers proceed)
            unsigned long long pv = ((unsigned long long)(unsigned)t << 32) |
                                    (unsigned long long)__float_as_uint(h);
            __hip_atomic_store(hbuf + (t & 1) * 32768u + (unsigned)gb * 512u + ar,
                               pv, __ATOMIC_RELAXED, __HIP_MEMORY_SCOPE_AGENT);
            hseq[eidx] = h;
            xwrd[eidx] = SC * (1.0f - th * th) * wl[er * 516 + ar];  // rdiag
        }
        __syncthreads();  // hp/part stable until epilogue done
    }
}

// y[p] = dot(hseq[p,:], out_w) + out_b;  one wave per (b,t)
__global__ __launch_bounds__(256) void y_proj(const float* __restrict__ hseq,
                                              const float* __restrict__ ow,
                                              const float* __restrict__ ob,
                                              float* __restrict__ y) {
    const int wave = threadIdx.x >> 6, lane = threadIdx.x & 63;
    const int p = blockIdx.x * 4 + wave;
    const float4* h4 = (const float4*)(hseq + (long long)p * 512);
    const float4* o4 = (const float4*)ow;
    float4 a0 = h4[lane * 2], a1 = h4[lane * 2 + 1];
    float4 b0 = o4[lane * 2], b1 = o4[lane * 2 + 1];
    float s = a0.x * b0.x + a0.y * b0.y + a0.z * b0.z + a0.w * b0.w +
              a1.x * b1.x + a1.y * b1.y + a1.z * b1.z + a1.w * b1.w;
#pragma unroll
    for (int off = 32; off > 0; off >>= 1) s += __shfl_down(s, off);
    if (lane == 0) y[p] = s + ob[0];
}

extern "C" void kernel_launch(void* const* d_in, const int* in_sizes, int n_in,
                              void* d_out, int out_size, void* d_ws, size_t ws_size,
                              hipStream_t stream) {
    const float* x   = (const float*)d_in[0];
    const float* Wxw = (const float*)d_in[1];
    const float* Wxb = (const float*)d_in[2];
    const float* Whw = (const float*)d_in[3];
    const float* ow  = (const float*)d_in[4];
    const float* ob  = (const float*)d_in[5];
    float* out   = (float*)d_out;
    float* y     = out + OFF_Y;
    float* hseq  = out + OFF_HSEQ;
    float* gate  = out + OFF_GATE;
    float* leak  = out + OFF_LEAK;
    float* rdiag = out + OFF_RDIAG;
    unsigned long long* hbuf = (unsigned long long*)d_ws;  // 2*64*512 u64 = 512 KB

    fill_consts<<<2048, 256, 0, stream>>>(gate, leak);
    xw_gemm<<<dim3(1024, 8), 256, 0, stream>>>(x, Wxw, Wxb, rdiag);

    {
        const float* WhA = Whw;
        float* xwrdA = rdiag;
        float* hseqA = hseq;
        unsigned long long* hbufA = hbuf;
        void* args[] = {(void*)&WhA, (void*)&xwrdA, (void*)&hseqA, (void*)&hbufA};
        hipLaunchCooperativeKernel((void*)scan_rnn, dim3(512), dim3(256), args, 0,
                                   stream);
    }

    y_proj<<<8192, 256, 0, stream>>>(hseq, ow, ob, y);
}